// Round 8
// baseline (641.078 us; speedup 1.0000x reference)
//
#include <hip/hip_runtime.h>
#include <math.h>

#define Bn 512
#define Tn 1024
#define Nn 64
#define LOG2E_F 1.44269504088896340736f
#define LN2_F   0.69314718055994530942f
#define BW 16            // batches per MFMA wave
#define NWF (Bn / BW)    // 32 fwd waves (+32 bwd)

typedef __attribute__((ext_vector_type(8))) short short8;   // 8 bf16
typedef __attribute__((ext_vector_type(4))) float f32x4;

__device__ __forceinline__ float wave_max(float v) {
    #pragma unroll
    for (int o = 32; o > 0; o >>= 1) v = fmaxf(v, __shfl_xor(v, o));
    return v;
}
__device__ __forceinline__ float wave_sum(float v) {
    #pragma unroll
    for (int o = 32; o > 0; o >>= 1) v += __shfl_xor(v, o);
    return v;
}
__device__ __forceinline__ short f2bf(float x) {            // RNE via compiler
    __bf16 h = (__bf16)x;
    return __builtin_bit_cast(short, h);
}
__device__ __forceinline__ float bf2f(short s) {
    __bf16 h = __builtin_bit_cast(__bf16, s);
    return (float)h;
}
__device__ __forceinline__ int clamp_row(int tt, int Lm1) {
    return tt < 0 ? 0 : (tt > Lm1 ? Lm1 : tt);
}

// ---------------------------------------------------------------------------
// MFMA recursion: 16 batches/wave. State S (64 tags x 16 batch) lives as
// fp32 q[4][4] in D-layout (tile m: tags 16m+4g+r, col batch = lane&15).
// D-regs == B-fragment k-slots (k = 4g+e | 16+4g+e, n = lane&15), so the
// next step's B operand is a pure in-lane fp32->bf16 repack. E^T is the
// stationary A operand (hi/lo split); 3-term MFMA product gives ~2^-18/step.
// fwd: q' = ex o (A x q);  bwd: q' = A x (ex o q). Per-batch lengths via
// freeze-select; renorm (scale-invariant) every 8 steps needs no freeze.
// ---------------------------------------------------------------------------

#define LOADX(dst, uu) do {                                        \
    int _t = clamp_row(t0 + dir * (uu), Lm1);                      \
    const float* _p = inb + (size_t)_t * Nn + 4 * g;               \
    dst[0] = *(const f32x4*)(_p);                                  \
    dst[1] = *(const f32x4*)(_p + 16);                             \
    dst[2] = *(const f32x4*)(_p + 32);                             \
    dst[3] = *(const f32x4*)(_p + 48);                             \
} while (0)

#define STEPM(X, kk) do {                                          \
    float ex_[4][4];                                               \
    _Pragma("unroll") for (int m_ = 0; m_ < 4; ++m_)               \
    _Pragma("unroll") for (int r_ = 0; r_ < 4; ++r_)               \
        ex_[m_][r_] = exp2f(fmaf(X[m_][r_], LOG2E_F, -6.0f));      \
    short8 bh_[2], bl_[2];                                         \
    _Pragma("unroll") for (int cc_ = 0; cc_ < 2; ++cc_) {          \
        _Pragma("unroll") for (int e_ = 0; e_ < 8; ++e_) {         \
            int m_ = 2 * cc_ + (e_ >> 2), r_ = e_ & 3;             \
            float v_ = bwd ? (q[m_][r_] * ex_[m_][r_]) : q[m_][r_];\
            short h_ = f2bf(v_);                                   \
            bh_[cc_][e_] = h_;                                     \
            bl_[cc_][e_] = f2bf(v_ - bf2f(h_));                    \
        }                                                          \
    }                                                              \
    f32x4 acc_[4];                                                 \
    _Pragma("unroll") for (int m_ = 0; m_ < 4; ++m_) {             \
        acc_[m_] = (f32x4){0.f, 0.f, 0.f, 0.f};                    \
        acc_[m_] = __builtin_amdgcn_mfma_f32_16x16x32_bf16(Ah[m_][0], bh_[0], acc_[m_], 0, 0, 0); \
        acc_[m_] = __builtin_amdgcn_mfma_f32_16x16x32_bf16(Ah[m_][1], bh_[1], acc_[m_], 0, 0, 0); \
        acc_[m_] = __builtin_amdgcn_mfma_f32_16x16x32_bf16(Al[m_][0], bh_[0], acc_[m_], 0, 0, 0); \
        acc_[m_] = __builtin_amdgcn_mfma_f32_16x16x32_bf16(Al[m_][1], bh_[1], acc_[m_], 0, 0, 0); \
        acc_[m_] = __builtin_amdgcn_mfma_f32_16x16x32_bf16(Ah[m_][0], bl_[0], acc_[m_], 0, 0, 0); \
        acc_[m_] = __builtin_amdgcn_mfma_f32_16x16x32_bf16(Ah[m_][1], bl_[1], acc_[m_], 0, 0, 0); \
    }                                                              \
    bool act_ = ((kk) < n_b);                                      \
    _Pragma("unroll") for (int m_ = 0; m_ < 4; ++m_)               \
    _Pragma("unroll") for (int r_ = 0; r_ < 4; ++r_) {             \
        float qn_ = bwd ? acc_[m_][r_] : (acc_[m_][r_] * ex_[m_][r_]); \
        q[m_][r_] = act_ ? qn_ : q[m_][r_];                        \
    }                                                              \
} while (0)

#define RENORM_COL() do {                                          \
    float pm_ = q[0][0];                                           \
    _Pragma("unroll") for (int m_ = 0; m_ < 4; ++m_)               \
    _Pragma("unroll") for (int r_ = 0; r_ < 4; ++r_)               \
        pm_ = fmaxf(pm_, q[m_][r_]);                               \
    pm_ = fmaxf(pm_, __shfl_xor(pm_, 16));                         \
    pm_ = fmaxf(pm_, __shfl_xor(pm_, 32));                         \
    float inv_ = 1.0f / pm_;                                       \
    _Pragma("unroll") for (int m_ = 0; m_ < 4; ++m_)               \
    _Pragma("unroll") for (int r_ = 0; r_ < 4; ++r_)               \
        q[m_][r_] *= inv_;                                         \
    base += __logf(pm_);                                           \
} while (0)

template <bool FULL>
__global__ __launch_bounds__(64, 1) void crf_mfma(
    const float* __restrict__ inputs, const float* __restrict__ trans,
    const int* __restrict__ tags, const int* __restrict__ lens,
    float* __restrict__ ws, float* __restrict__ out)
{
    const int j = threadIdx.x;

    // ---- score role: blocks [2*NWF, 2*NWF+Bn) -- runs on the ~190 CUs the
    // 64 recursion blocks don't occupy; truly concurrent this time.
    if (!FULL && blockIdx.x >= 2 * NWF) {
        const int b = blockIdx.x - 2 * NWF;
        const int L = lens[b];
        const int* tagb = tags + b * Tn;
        const float* inb = inputs + (size_t)b * Tn * Nn;
        float sacc = 0.f;
        #pragma unroll
        for (int i = 0; i < Tn / 64; ++i) {
            int t  = j + 64 * i;
            int tm = t > 0 ? t - 1 : 0;
            int tg = tagb[t];
            int tp = tagb[tm];
            float un = inb[t * Nn + tg];
            float bi = trans[tp * Nn + tg];
            float c  = un + ((t >= 1) ? bi : 0.f);
            sacc += (t < L) ? c : 0.f;
        }
        float sc = wave_sum(sacc);
        if (j == 0) out[b] = sc;
        return;
    }

    const bool bwd = (!FULL) && (blockIdx.x >= NWF);
    const int wid = bwd ? (blockIdx.x - NWF) : blockIdx.x;
    const int c = j & 15;          // batch column (B n-index / A m-index)
    const int g = j >> 4;          // k-group / D row-group
    const int b = wid * BW + c;
    const int L = lens[b];
    const int Lm1 = L - 1;
    const float* inb = inputs + (size_t)b * Tn * Nn;

    // ---- stationary A = E^T fragments (hi/lo), built once ----
    // A-layout: row = lane&15, k = 4*(lane>>4)+e (e<4) | 16+4*(lane>>4)+(e-4)
    short8 Ah[4][2], Al[4][2];
    #pragma unroll
    for (int m = 0; m < 4; ++m)
    #pragma unroll
    for (int kc = 0; kc < 2; ++kc) {
        #pragma unroll
        for (int e = 0; e < 8; ++e) {
            int ksub = (e < 4) ? (4 * g + e) : (16 + 4 * g + e - 4);
            int i = kc * 32 + ksub;                 // input tag (k)
            int o = m * 16 + c;                     // output tag (A row)
            float tv = bwd ? trans[o * 64 + i] : trans[i * 64 + o];
            float v = exp2f(tv * LOG2E_F);
            short h = f2bf(v);
            Ah[m][kc][e] = h;
            Al[m][kc][e] = f2bf(v - bf2f(h));
        }
    }

    float q[4][4];
    float base;
    int n_b, t0, dir;
    if (!bwd) {
        f32x4 x0[4];
        const float* p0 = inb + 4 * g;
        x0[0] = *(const f32x4*)(p0);
        x0[1] = *(const f32x4*)(p0 + 16);
        x0[2] = *(const f32x4*)(p0 + 32);
        x0[3] = *(const f32x4*)(p0 + 48);
        float pm = x0[0][0];
        #pragma unroll
        for (int m = 0; m < 4; ++m)
        #pragma unroll
        for (int r = 0; r < 4; ++r) pm = fmaxf(pm, x0[m][r]);
        pm = fmaxf(pm, __shfl_xor(pm, 16));
        pm = fmaxf(pm, __shfl_xor(pm, 32));
        #pragma unroll
        for (int m = 0; m < 4; ++m)
        #pragma unroll
        for (int r = 0; r < 4; ++r)
            q[m][r] = exp2f((x0[m][r] - pm) * LOG2E_F);
        base = pm;
        n_b = FULL ? Lm1 : (L >> 1);
        t0 = 1; dir = 1;
    } else {
        #pragma unroll
        for (int m = 0; m < 4; ++m)
        #pragma unroll
        for (int r = 0; r < 4; ++r) q[m][r] = 1.f;
        base = 0.f;
        n_b = Lm1 - (L >> 1);
        t0 = Lm1; dir = -1;
    }

    int nmax = (int)wave_max((float)n_b);
    nmax = __builtin_amdgcn_readfirstlane(nmax);

    // 2-step lookahead prefetch (unconditional clamped loads, R3 lesson)
    f32x4 xq0[4], xq1[4], xn0[4], xn1[4];
    LOADX(xq0, 0);
    LOADX(xq1, 1);

    for (int k = 0; k < nmax; k += 2) {
        LOADX(xn0, k + 2);
        LOADX(xn1, k + 3);
        STEPM(xq0, k);
        STEPM(xq1, k + 1);
        if (((k + 2) & 7) == 0) RENORM_COL();
        #pragma unroll
        for (int m = 0; m < 4; ++m) { xq0[m] = xn0[m]; xq1[m] = xn1[m]; }
    }

    // final renorm + per-step 1/64 bias correction (per-batch n_b)
    {
        float pm = q[0][0];
        #pragma unroll
        for (int m = 0; m < 4; ++m)
        #pragma unroll
        for (int r = 0; r < 4; ++r) pm = fmaxf(pm, q[m][r]);
        pm = fmaxf(pm, __shfl_xor(pm, 16));
        pm = fmaxf(pm, __shfl_xor(pm, 32));
        float inv = 1.0f / pm;
        #pragma unroll
        for (int m = 0; m < 4; ++m)
        #pragma unroll
        for (int r = 0; r < 4; ++r) q[m][r] *= inv;
        base += __logf(pm) + LN2_F * 6.0f * (float)n_b;
    }

    if (FULL) {
        float s = 0.f;
        #pragma unroll
        for (int m = 0; m < 4; ++m)
        #pragma unroll
        for (int r = 0; r < 4; ++r) s += q[m][r];
        s += __shfl_xor(s, 16);
        s += __shfl_xor(s, 32);
        if (g == 0) out[b] -= (base + __logf(s));
    } else {
        float* fvec = ws;
        float* gvec = ws + Bn * 64;
        float* fb   = ws + 2 * Bn * 64;
        float* gb   = fb + Bn;
        float* vec  = bwd ? gvec : fvec;
        #pragma unroll
        for (int m = 0; m < 4; ++m)
        #pragma unroll
        for (int r = 0; r < 4; ++r)
            vec[b * 64 + m * 16 + 4 * g + r] = q[m][r];
        if (g == 0) { if (bwd) gb[b] = base; else fb[b] = base; }
    }
}

// ---------------------------------------------------------------------------
// scores standalone (fallback path only)
// ---------------------------------------------------------------------------
__global__ __launch_bounds__(256) void crf_scores(
    const float* __restrict__ inputs, const float* __restrict__ trans,
    const int* __restrict__ tags, const int* __restrict__ lens,
    float* __restrict__ out)
{
    const int b = blockIdx.x;
    const int L = lens[b];
    const int* tagb = tags + b * Tn;
    const float* inb = inputs + (size_t)b * Tn * Nn;

    float acc = 0.f;
    for (int t = threadIdx.x; t < L; t += 256) {
        int tg = tagb[t];
        acc += inb[t * Nn + tg];
        if (t >= 1) acc += trans[tagb[t - 1] * Nn + tg];
    }
    acc = wave_sum(acc);
    __shared__ float red[4];
    if ((threadIdx.x & 63) == 0) red[threadIdx.x >> 6] = acc;
    __syncthreads();
    if (threadIdx.x == 0) out[b] = (red[0] + red[1]) + (red[2] + red[3]);
}

// ---------------------------------------------------------------------------
// combine halves: logZ = log(f . g) + fbase + gbase; out[b] -= logZ
// ---------------------------------------------------------------------------
__global__ __launch_bounds__(64, 1) void crf_combine(
    const float* __restrict__ ws, float* __restrict__ out)
{
    const int b = blockIdx.x;
    const int j = threadIdx.x;
    const float* fvec = ws;
    const float* gvec = ws + Bn * 64;
    const float* fb   = ws + 2 * Bn * 64;
    const float* gb   = fb + Bn;

    float p = wave_sum(fvec[b * 64 + j] * gvec[b * 64 + j]);
    if (j == 0) out[b] -= (__logf(p) + fb[b] + gb[b]);
}

extern "C" void kernel_launch(void* const* d_in, const int* in_sizes, int n_in,
                              void* d_out, int out_size, void* d_ws, size_t ws_size,
                              hipStream_t stream) {
    const float* inputs = (const float*)d_in[0];
    const float* trans  = (const float*)d_in[1];
    const int*   tags   = (const int*)d_in[2];
    const int*   lens   = (const int*)d_in[3];
    float* out = (float*)d_out;
    float* ws  = (float*)d_ws;

    const size_t need = (size_t)(2 * Bn * 64 + 2 * Bn) * sizeof(float);
    if (ws_size >= need) {
        // 32 fwd + 32 bwd MFMA waves + 512 concurrent score blocks
        crf_mfma<false><<<2 * NWF + Bn, 64, 0, stream>>>(inputs, trans, tags, lens, ws, out);
        crf_combine<<<Bn, 64, 0, stream>>>(ws, out);
    } else {
        // workspace too small: score kernel + full-length fwd recursion
        crf_scores<<<Bn, 256, 0, stream>>>(inputs, trans, tags, lens, out);
        crf_mfma<true><<<NWF, 64, 0, stream>>>(inputs, trans, tags, lens, ws, out);
    }
}

// Round 9
// 623.466 us; speedup vs baseline: 1.0282x; 1.0282x over previous
//
#include <hip/hip_runtime.h>
#include <math.h>

#define Bn 512
#define Tn 1024
#define Nn 64
#define LOG2E_F 1.44269504088896340736f
#define LN2_F   0.69314718055994530942f
#define BW 16            // batches per MFMA wave
#define NWF (Bn / BW)    // 32 fwd waves (+32 bwd)
#define SS 4             // steps per LDS stage
#define LROW 68          // padded LDS row (floats): banks 17c+g, conflict-free

typedef __attribute__((ext_vector_type(8))) short short8;   // 8 bf16
typedef __attribute__((ext_vector_type(4))) float f32x4;

__device__ __forceinline__ float wave_max(float v) {
    #pragma unroll
    for (int o = 32; o > 0; o >>= 1) v = fmaxf(v, __shfl_xor(v, o));
    return v;
}
__device__ __forceinline__ float wave_sum(float v) {
    #pragma unroll
    for (int o = 32; o > 0; o >>= 1) v += __shfl_xor(v, o);
    return v;
}
__device__ __forceinline__ short f2bf(float x) {            // RNE via compiler
    __bf16 h = (__bf16)x;
    return __builtin_bit_cast(short, h);
}
__device__ __forceinline__ float bf2f(short s) {
    __bf16 h = __builtin_bit_cast(__bf16, s);
    return (float)h;
}
__device__ __forceinline__ int clamp_row(int tt, int Lm1) {
    return tt < 0 ? 0 : (tt > Lm1 ? Lm1 : tt);
}

// ---------------------------------------------------------------------------
// MFMA recursion, 16 batches/wave (R8 layout, feed path rebuilt in R9):
//  - state q[4][4] fp32 in D-layout (tile m: tags 16m+4g+r, col = batch c)
//  - D-regs == B-fragment k-slots -> in-lane repack only, no cross-lane
//  - stationary A = E^T hi/lo split-bf16, 3-term product (~2^-18/step)
// R9 feed: R8's per-lane gathers (16 lines/instr, ~1900 cyc stall/step,
// VALUBusy 3.5%) replaced by coalesced stage loads (16-lane group = one
// 256B seq row) + LDS transpose [SS][16][68] double-buffered. exp2f applied
// to staged regs BEFORE ds_write: LDS holds e^x/64, exp off the chain.
// Per-step feed: 4x ds_read_b128, banks 17c+g (pad 68) ~conflict-free.
// ---------------------------------------------------------------------------

// stage loads: instruction i -> step u=i>>2, seq s=g+4*(i&3); lane reads
// elements 4c..4c+3 of row t(u) of seq s. 4 contiguous 256B rows / instr.
#define SLOAD(kb_) do {                                            \
    _Pragma("unroll")                                              \
    for (int i_ = 0; i_ < 16; ++i_) {                              \
        int u_ = i_ >> 2, q_ = i_ & 3;                             \
        int t_ = clamp_row(t0s4[q_] + dir * ((kb_) + u_), Lm14[q_]); \
        stg[i_] = *(const f32x4*)(sp4[q_] + (size_t)t_ * Nn + 4 * c); \
    }                                                              \
} while (0)

// exp + transpose-write into LDS buffer tb_
#define SCOMMIT(tb_) do {                                          \
    _Pragma("unroll")                                              \
    for (int i_ = 0; i_ < 16; ++i_) {                              \
        int u_ = i_ >> 2, q_ = i_ & 3;                             \
        int s_ = g + 4 * q_;                                       \
        f32x4 e_;                                                  \
        _Pragma("unroll")                                          \
        for (int r_ = 0; r_ < 4; ++r_)                             \
            e_[r_] = exp2f(fmaf(stg[i_][r_], LOG2E_F, -6.0f));     \
        *(f32x4*)&exl[(((tb_) * SS + u_) * 16 + s_) * LROW + 4 * c] = e_; \
    }                                                              \
} while (0)

// one recursion step fed by pre-exp'ed EXV (f32x4[4], elem 16m+4g+r)
#define STEPM(EXV, kk) do {                                        \
    short8 bh_[2], bl_[2];                                         \
    _Pragma("unroll") for (int cc_ = 0; cc_ < 2; ++cc_) {          \
        _Pragma("unroll") for (int e_ = 0; e_ < 8; ++e_) {         \
            int m_ = 2 * cc_ + (e_ >> 2), r_ = e_ & 3;             \
            float v_ = bwd ? (q[m_][r_] * EXV[m_][r_]) : q[m_][r_];\
            short h_ = f2bf(v_);                                   \
            bh_[cc_][e_] = h_;                                     \
            bl_[cc_][e_] = f2bf(v_ - bf2f(h_));                    \
        }                                                          \
    }                                                              \
    bool act_ = ((kk) < n_b);                                      \
    _Pragma("unroll") for (int m_ = 0; m_ < 4; ++m_) {             \
        f32x4 a0_ = (f32x4){0.f, 0.f, 0.f, 0.f};                   \
        f32x4 a1_ = (f32x4){0.f, 0.f, 0.f, 0.f};                   \
        a0_ = __builtin_amdgcn_mfma_f32_16x16x32_bf16(Ah[m_][0], bh_[0], a0_, 0, 0, 0); \
        a1_ = __builtin_amdgcn_mfma_f32_16x16x32_bf16(Ah[m_][1], bh_[1], a1_, 0, 0, 0); \
        a0_ = __builtin_amdgcn_mfma_f32_16x16x32_bf16(Al[m_][0], bh_[0], a0_, 0, 0, 0); \
        a1_ = __builtin_amdgcn_mfma_f32_16x16x32_bf16(Al[m_][1], bh_[1], a1_, 0, 0, 0); \
        a0_ = __builtin_amdgcn_mfma_f32_16x16x32_bf16(Ah[m_][0], bl_[0], a0_, 0, 0, 0); \
        a1_ = __builtin_amdgcn_mfma_f32_16x16x32_bf16(Ah[m_][1], bl_[1], a1_, 0, 0, 0); \
        _Pragma("unroll") for (int r_ = 0; r_ < 4; ++r_) {         \
            float s_ = a0_[r_] + a1_[r_];                          \
            float qn_ = bwd ? s_ : (s_ * EXV[m_][r_]);             \
            q[m_][r_] = act_ ? qn_ : q[m_][r_];                    \
        }                                                          \
    }                                                              \
} while (0)

#define RENORM_COL() do {                                          \
    float pm_ = q[0][0];                                           \
    _Pragma("unroll") for (int m_ = 0; m_ < 4; ++m_)               \
    _Pragma("unroll") for (int r_ = 0; r_ < 4; ++r_)               \
        pm_ = fmaxf(pm_, q[m_][r_]);                               \
    pm_ = fmaxf(pm_, __shfl_xor(pm_, 16));                         \
    pm_ = fmaxf(pm_, __shfl_xor(pm_, 32));                         \
    float inv_ = 1.0f / pm_;                                       \
    _Pragma("unroll") for (int m_ = 0; m_ < 4; ++m_)               \
    _Pragma("unroll") for (int r_ = 0; r_ < 4; ++r_)               \
        q[m_][r_] *= inv_;                                         \
    base += __logf(pm_);                                           \
} while (0)

template <bool FULL>
__global__ __launch_bounds__(64, 1) void crf_mfma(
    const float* __restrict__ inputs, const float* __restrict__ trans,
    const int* __restrict__ tags, const int* __restrict__ lens,
    float* __restrict__ ws, float* __restrict__ out)
{
    const int j = threadIdx.x;

    // ---- score role: blocks [2*NWF, 2*NWF+Bn) on otherwise-idle CUs
    if (!FULL && blockIdx.x >= 2 * NWF) {
        const int b = blockIdx.x - 2 * NWF;
        const int L = lens[b];
        const int* tagb = tags + b * Tn;
        const float* inb = inputs + (size_t)b * Tn * Nn;
        float sacc = 0.f;
        #pragma unroll
        for (int i = 0; i < Tn / 64; ++i) {
            int t  = j + 64 * i;
            int tm = t > 0 ? t - 1 : 0;
            int tg = tagb[t];
            int tp = tagb[tm];
            float un = inb[t * Nn + tg];
            float bi = trans[tp * Nn + tg];
            float c  = un + ((t >= 1) ? bi : 0.f);
            sacc += (t < L) ? c : 0.f;
        }
        float sc = wave_sum(sacc);
        if (j == 0) out[b] = sc;
        return;
    }

    const bool bwd = (!FULL) && (blockIdx.x >= NWF);
    const int wid = bwd ? (blockIdx.x - NWF) : blockIdx.x;
    const int c = j & 15;          // batch column (B n-index / A row m-index)
    const int g = j >> 4;          // k-group / D row-group / staging group
    const int b0 = wid * BW;
    const int b = b0 + c;
    const int L = lens[b];
    const int Lm1 = L - 1;
    const float* inb = inputs + (size_t)b * Tn * Nn;

    __shared__ __align__(16) float exl[2 * SS * 16 * LROW];

    // ---- stationary A = E^T fragments (hi/lo), built once ----
    short8 Ah[4][2], Al[4][2];
    #pragma unroll
    for (int m = 0; m < 4; ++m)
    #pragma unroll
    for (int kc = 0; kc < 2; ++kc) {
        #pragma unroll
        for (int e = 0; e < 8; ++e) {
            int ksub = (e < 4) ? (4 * g + e) : (16 + 4 * g + e - 4);
            int i = kc * 32 + ksub;                 // input tag (k)
            int o = m * 16 + c;                     // output tag (A row)
            float tv = bwd ? trans[o * 64 + i] : trans[i * 64 + o];
            float v = exp2f(tv * LOG2E_F);
            short h = f2bf(v);
            Ah[m][kc][e] = h;
            Al[m][kc][e] = f2bf(v - bf2f(h));
        }
    }

    float q[4][4];
    float base;
    int n_b, t0, dir;
    if (!bwd) {
        f32x4 x0[4];
        const float* p0 = inb + 4 * g;
        x0[0] = *(const f32x4*)(p0);
        x0[1] = *(const f32x4*)(p0 + 16);
        x0[2] = *(const f32x4*)(p0 + 32);
        x0[3] = *(const f32x4*)(p0 + 48);
        float pm = x0[0][0];
        #pragma unroll
        for (int m = 0; m < 4; ++m)
        #pragma unroll
        for (int r = 0; r < 4; ++r) pm = fmaxf(pm, x0[m][r]);
        pm = fmaxf(pm, __shfl_xor(pm, 16));
        pm = fmaxf(pm, __shfl_xor(pm, 32));
        #pragma unroll
        for (int m = 0; m < 4; ++m)
        #pragma unroll
        for (int r = 0; r < 4; ++r)
            q[m][r] = exp2f((x0[m][r] - pm) * LOG2E_F);
        base = pm;
        n_b = FULL ? Lm1 : (L >> 1);
        t0 = 1; dir = 1;
    } else {
        #pragma unroll
        for (int m = 0; m < 4; ++m)
        #pragma unroll
        for (int r = 0; r < 4; ++r) q[m][r] = 1.f;
        base = 0.f;
        n_b = Lm1 - (L >> 1);
        t0 = Lm1; dir = -1;
    }

    // per-staging-lane tables: this lane stages seqs s = g + 4*qi
    int Lm14[4], t0s4[4];
    const float* sp4[4];
    #pragma unroll
    for (int qi = 0; qi < 4; ++qi) {
        int Ls = __shfl(L, g + 4 * qi);      // lane s<16 holds lens[b0+s]
        Lm14[qi] = Ls - 1;
        t0s4[qi] = bwd ? (Ls - 1) : 1;
        sp4[qi] = inputs + (size_t)(b0 + g + 4 * qi) * Tn * Nn;
    }

    int nmax = (int)wave_max((float)n_b);
    nmax = __builtin_amdgcn_readfirstlane(nmax);

    // ---- staged pipeline: regs (coalesced) -> exp -> LDS -> per-step reads
    f32x4 stg[16];
    SLOAD(0);
    SCOMMIT(0);                     // steps 0..3 in buffer 0
    SLOAD(SS);                      // steps 4..7 in flight

    for (int kb = 0; kb < nmax; kb += SS) {
        const int cb = (kb >> 2) & 1;
        #pragma unroll
        for (int u = 0; u < SS; ++u) {
            f32x4 exv[4];
            #pragma unroll
            for (int m = 0; m < 4; ++m)
                exv[m] = *(const f32x4*)&exl[((cb * SS + u) * 16 + c) * LROW + 16 * m + 4 * g];
            STEPM(exv, kb + u);
        }
        if (((kb + SS) & 7) == 0) RENORM_COL();
        SCOMMIT(cb ^ 1);            // next 4 steps (loads had a full stage)
        SLOAD(kb + 2 * SS);         // issue following stage's loads
    }

    // final renorm + per-step 1/64 bias correction (per-batch n_b)
    {
        float pm = q[0][0];
        #pragma unroll
        for (int m = 0; m < 4; ++m)
        #pragma unroll
        for (int r = 0; r < 4; ++r) pm = fmaxf(pm, q[m][r]);
        pm = fmaxf(pm, __shfl_xor(pm, 16));
        pm = fmaxf(pm, __shfl_xor(pm, 32));
        float inv = 1.0f / pm;
        #pragma unroll
        for (int m = 0; m < 4; ++m)
        #pragma unroll
        for (int r = 0; r < 4; ++r) q[m][r] *= inv;
        base += __logf(pm) + LN2_F * 6.0f * (float)n_b;
    }

    if (FULL) {
        float s = 0.f;
        #pragma unroll
        for (int m = 0; m < 4; ++m)
        #pragma unroll
        for (int r = 0; r < 4; ++r) s += q[m][r];
        s += __shfl_xor(s, 16);
        s += __shfl_xor(s, 32);
        if (g == 0) out[b] -= (base + __logf(s));
    } else {
        float* fvec = ws;
        float* gvec = ws + Bn * 64;
        float* fb   = ws + 2 * Bn * 64;
        float* gb   = fb + Bn;
        float* vec  = bwd ? gvec : fvec;
        #pragma unroll
        for (int m = 0; m < 4; ++m)
        #pragma unroll
        for (int r = 0; r < 4; ++r)
            vec[b * 64 + m * 16 + 4 * g + r] = q[m][r];
        if (g == 0) { if (bwd) gb[b] = base; else fb[b] = base; }
    }
}

// ---------------------------------------------------------------------------
// scores standalone (fallback path only)
// ---------------------------------------------------------------------------
__global__ __launch_bounds__(256) void crf_scores(
    const float* __restrict__ inputs, const float* __restrict__ trans,
    const int* __restrict__ tags, const int* __restrict__ lens,
    float* __restrict__ out)
{
    const int b = blockIdx.x;
    const int L = lens[b];
    const int* tagb = tags + b * Tn;
    const float* inb = inputs + (size_t)b * Tn * Nn;

    float acc = 0.f;
    for (int t = threadIdx.x; t < L; t += 256) {
        int tg = tagb[t];
        acc += inb[t * Nn + tg];
        if (t >= 1) acc += trans[tagb[t - 1] * Nn + tg];
    }
    acc = wave_sum(acc);
    __shared__ float red[4];
    if ((threadIdx.x & 63) == 0) red[threadIdx.x >> 6] = acc;
    __syncthreads();
    if (threadIdx.x == 0) out[b] = (red[0] + red[1]) + (red[2] + red[3]);
}

// ---------------------------------------------------------------------------
// combine halves: logZ = log(f . g) + fbase + gbase; out[b] -= logZ
// ---------------------------------------------------------------------------
__global__ __launch_bounds__(64, 1) void crf_combine(
    const float* __restrict__ ws, float* __restrict__ out)
{
    const int b = blockIdx.x;
    const int j = threadIdx.x;
    const float* fvec = ws;
    const float* gvec = ws + Bn * 64;
    const float* fb   = ws + 2 * Bn * 64;
    const float* gb   = fb + Bn;

    float p = wave_sum(fvec[b * 64 + j] * gvec[b * 64 + j]);
    if (j == 0) out[b] -= (__logf(p) + fb[b] + gb[b]);
}

extern "C" void kernel_launch(void* const* d_in, const int* in_sizes, int n_in,
                              void* d_out, int out_size, void* d_ws, size_t ws_size,
                              hipStream_t stream) {
    const float* inputs = (const float*)d_in[0];
    const float* trans  = (const float*)d_in[1];
    const int*   tags   = (const int*)d_in[2];
    const int*   lens   = (const int*)d_in[3];
    float* out = (float*)d_out;
    float* ws  = (float*)d_ws;

    const size_t need = (size_t)(2 * Bn * 64 + 2 * Bn) * sizeof(float);
    if (ws_size >= need) {
        // 32 fwd + 32 bwd MFMA waves + 512 concurrent score blocks
        crf_mfma<false><<<2 * NWF + Bn, 64, 0, stream>>>(inputs, trans, tags, lens, ws, out);
        crf_combine<<<Bn, 64, 0, stream>>>(ws, out);
    } else {
        // workspace too small: score kernel + full-length fwd recursion
        crf_scores<<<Bn, 256, 0, stream>>>(inputs, trans, tags, lens, out);
        crf_mfma<true><<<NWF, 64, 0, stream>>>(inputs, trans, tags, lens, ws, out);
    }
}

// Round 10
// 323.794 us; speedup vs baseline: 1.9799x; 1.9255x over previous
//
#include <hip/hip_runtime.h>
#include <math.h>

#define Bn 512
#define Tn 1024
#define Nn 64
#define LOG2E_F 1.44269504088896340736f
#define LN2_F   0.69314718055994530942f

typedef __attribute__((ext_vector_type(2))) float f32x2;

__device__ __forceinline__ float wave_max(float v) {
    #pragma unroll
    for (int o = 32; o > 0; o >>= 1) v = fmaxf(v, __shfl_xor(v, o));
    return v;
}
__device__ __forceinline__ float wave_sum(float v) {
    #pragma unroll
    for (int o = 32; o > 0; o >>= 1) v += __shfl_xor(v, o);
    return v;
}

// ---------------------------------------------------------------------------
// Main kernel, role by blockIdx (R7 structure = measured best, 168.5us):
//   [0, Bn)     forward recursion half   [Bn, 2Bn)  backward half
//   [2Bn, 3Bn)  unary+binary scores (fills idle wave slots concurrently)
//
// R8/R9 post-mortem: MFMA recursion = ~2500 cyc/step regardless of feed
// path (gathers vs staged LDS) -> stall intrinsic to D->repack->B serial
// core; abandoned after two failed predictions.
// R10: back to the 687-cyc/step LDS-broadcast chain; halve its FMA-issue
// component (128 cyc) with v_pk_fma_f32 -- outputs {p, p+32} packed as
// f32x2 acc, E columns pre-paired as f32x2. 32 pk-FMAs/step vs 64 scalar.
//
// Serial-chain budget (R4 counters: 687 cyc/step, VALUBusy 24%):
//   ds_write->ds_read data ~140 | 8x ds_read_b128 ~96 |
//   FMA issue 128 -> 64 (R10) | shfl_xor(32) ~110 | misc/waits ~200
// ---------------------------------------------------------------------------

// one recursion step; exact fp32. Single wave: LDS queue is in-order per
// wave, so write -> reads needs no barrier.
#define STEP2(BWDV, EXV) do {                                      \
    shq[j] = (BWDV) ? ((EXV) * q) : q;                             \
    f32x2 _a0 = {0.f, 0.f}, _a1 = {0.f, 0.f};                      \
    f32x2 _a2 = {0.f, 0.f}, _a3 = {0.f, 0.f};                      \
    _Pragma("unroll")                                              \
    for (int _cb = 0; _cb < 8; ++_cb) {                            \
        float4 _qv = *(const float4*)&shq[(g << 5) + (_cb << 2)];  \
        _a0 = __builtin_elementwise_fma((f32x2){_qv.x, _qv.x}, EfPQ[4*_cb + 0], _a0); \
        _a1 = __builtin_elementwise_fma((f32x2){_qv.y, _qv.y}, EfPQ[4*_cb + 1], _a1); \
        _a2 = __builtin_elementwise_fma((f32x2){_qv.z, _qv.z}, EfPQ[4*_cb + 2], _a2); \
        _a3 = __builtin_elementwise_fma((f32x2){_qv.w, _qv.w}, EfPQ[4*_cb + 3], _a3); \
    }                                                              \
    f32x2 _s2 = (_a0 + _a1) + (_a2 + _a3);                         \
    float _u = lo32 ? _s2[0] : _s2[1];                             \
    float _w = lo32 ? _s2[1] : _s2[0];                             \
    float _s = _u + __shfl_xor(_w, 32);                            \
    q = (BWDV) ? _s : ((EXV) * _s);                                \
} while (0)

// clamped row index: keeps every prefetch load unconditional + in-bounds
__device__ __forceinline__ int clamp_row(int tt, int Lm1) {
    return tt < 0 ? 0 : (tt > Lm1 ? Lm1 : tt);
}

template <bool FULL>
__global__ __launch_bounds__(64, 1) void crf_main(
    const float* __restrict__ inputs, const float* __restrict__ trans,
    const int* __restrict__ tags, const int* __restrict__ lens,
    float* __restrict__ ws, float* __restrict__ out)
{
    const int j = threadIdx.x;

    // ---- score role: one wave per b, fills idle slots alongside recursion
    if (!FULL && blockIdx.x >= 2 * Bn) {
        const int b = blockIdx.x - 2 * Bn;
        const int L = lens[b];
        const int* tagb = tags + b * Tn;
        const float* inb = inputs + (size_t)b * Tn * Nn;
        float sacc = 0.f;
        #pragma unroll
        for (int i = 0; i < Tn / 64; ++i) {
            int t  = j + 64 * i;
            int tm = t > 0 ? t - 1 : 0;
            int tg = tagb[t];
            int tp = tagb[tm];
            float un = inb[t * Nn + tg];
            float bi = trans[tp * Nn + tg];
            float c  = un + ((t >= 1) ? bi : 0.f);
            sacc += (t < L) ? c : 0.f;
        }
        float sc = wave_sum(sacc);
        if (j == 0) out[b] = sc;
        return;
    }

    const int g = j >> 5;            // input K-half this lane reads
    const int p = j & 31;
    const bool lo32 = (j < 32);
    const bool bwd = (!FULL) && (blockIdx.x >= Bn);
    const int b = bwd ? (blockIdx.x - Bn) : blockIdx.x;
    const int L = lens[b];
    const int Lm1 = L - 1;
    const float* inb = inputs + (size_t)b * Tn * Nn;

    // EfPQ[c] = {weight of input (g*32+c) -> output p, -> output p+32}
    f32x2 EfPQ[32];
    __shared__ float trsh[64 * 65];
    __shared__ __align__(16) float shq[64];
    if (!bwd) {
        // fwd: E[i][o] = exp(trans[i*64+o])
        #pragma unroll
        for (int c = 0; c < 32; ++c) {
            EfPQ[c][0] = exp2f(trans[(g * 32 + c) * 64 + p     ] * LOG2E_F);
            EfPQ[c][1] = exp2f(trans[(g * 32 + c) * 64 + p + 32] * LOG2E_F);
        }
    } else {
        // bwd: E[o][i] = exp(trans[o*64+i]); transpose-gather via LDS
        #pragma unroll
        for (int i = 0; i < 64; ++i) trsh[i * 65 + j] = trans[i * 64 + j];
        __syncthreads();
        #pragma unroll
        for (int c = 0; c < 32; ++c) {
            EfPQ[c][0] = exp2f(trsh[p        * 65 + g * 32 + c] * LOG2E_F);
            EfPQ[c][1] = exp2f(trsh[(p + 32) * 65 + g * 32 + c] * LOG2E_F);
        }
    }

    float q, base;
    int t0, dir, n;
    const int tf = L >> 1;           // forward covers t in [1,tf], backward (tf, L-1]
    if (!bwd) {
        float x0 = inb[j];
        float m = wave_max(x0);
        q = exp2f((x0 - m) * LOG2E_F);
        base = m;
        t0 = 1; dir = 1;
        n = FULL ? (L - 1) : tf;
    } else {
        q = 1.f; base = 0.f;
        t0 = L - 1; dir = -1;
        n = (L - 1) - tf;
    }

    // current 8-row register buffer (unconditional clamped loads)
    float xc[8];
    #pragma unroll
    for (int d = 0; d < 8; ++d)
        xc[d] = inb[clamp_row(t0 + d * dir, Lm1) * Nn + j];

    int t = t0;
    int k = 0;
    float pend = 1.0f;               // deferred 1/m from previous superstep

    if (!bwd) {
        while (k + 8 <= n) {
            float xn[8];
            #pragma unroll
            for (int d = 0; d < 8; ++d)
                xn[d] = inb[clamp_row(t + (8 + d) * dir, Lm1) * Nn + j];
            float exc[8];
            #pragma unroll
            for (int u = 0; u < 8; ++u)
                exc[u] = exp2f(fmaf(xc[u], LOG2E_F, -6.0f));
            exc[2] *= pend;          // apply deferred renorm off the chain
            #pragma unroll
            for (int u = 0; u < 8; ++u) STEP2(false, exc[u]);
            float m = wave_max(q);   // latency hides under next superstep
            base += __logf(m);
            pend = 1.0f / m;
            #pragma unroll
            for (int d = 0; d < 8; ++d) xc[d] = xn[d];
            k += 8; t += 8;
        }
        q *= pend; pend = 1.0f;
        #pragma unroll
        for (int u = 0; u < 8; ++u) {
            if (k + u < n) {
                float exu = exp2f(fmaf(xc[u], LOG2E_F, -6.0f));
                STEP2(false, exu);
            }
        }
    } else {
        while (k + 8 <= n) {
            float xn[8];
            #pragma unroll
            for (int d = 0; d < 8; ++d)
                xn[d] = inb[clamp_row(t - (8 + d), Lm1) * Nn + j];
            float exc[8];
            #pragma unroll
            for (int u = 0; u < 8; ++u)
                exc[u] = exp2f(fmaf(xc[u], LOG2E_F, -6.0f));
            exc[2] *= pend;
            #pragma unroll
            for (int u = 0; u < 8; ++u) STEP2(true, exc[u]);
            float m = wave_max(q);
            base += __logf(m);
            pend = 1.0f / m;
            #pragma unroll
            for (int d = 0; d < 8; ++d) xc[d] = xn[d];
            k += 8; t -= 8;
        }
        q *= pend; pend = 1.0f;
        #pragma unroll
        for (int u = 0; u < 8; ++u) {
            if (k + u < n) {
                float exu = exp2f(fmaf(xc[u], LOG2E_F, -6.0f));
                STEP2(true, exu);
            }
        }
    }

    // final renorm + account for the per-step 1/64 scaling
    {
        float m = wave_max(q);
        q *= (1.0f / m);
        base += __logf(m) + LN2_F * 6.0f * (float)n;
    }

    if (FULL) {
        float ssum = wave_sum(q);
        if (j == 0) out[b] -= (base + __logf(ssum));
    } else {
        float* fvec = ws;
        float* gvec = ws + Bn * 64;
        float* fb   = ws + 2 * Bn * 64;
        float* gb   = fb + Bn;
        if (!bwd) { fvec[b * 64 + j] = q; if (j == 0) fb[b] = base; }
        else      { gvec[b * 64 + j] = q; if (j == 0) gb[b] = base; }
    }
}

// ---------------------------------------------------------------------------
// scores standalone (fallback path only)
// ---------------------------------------------------------------------------
__global__ __launch_bounds__(256) void crf_scores(
    const float* __restrict__ inputs, const float* __restrict__ trans,
    const int* __restrict__ tags, const int* __restrict__ lens,
    float* __restrict__ out)
{
    const int b = blockIdx.x;
    const int L = lens[b];
    const int* tagb = tags + b * Tn;
    const float* inb = inputs + (size_t)b * Tn * Nn;

    float acc = 0.f;
    for (int t = threadIdx.x; t < L; t += 256) {
        int tg = tagb[t];
        acc += inb[t * Nn + tg];
        if (t >= 1) acc += trans[tagb[t - 1] * Nn + tg];
    }
    acc = wave_sum(acc);
    __shared__ float red[4];
    if ((threadIdx.x & 63) == 0) red[threadIdx.x >> 6] = acc;
    __syncthreads();
    if (threadIdx.x == 0) out[b] = (red[0] + red[1]) + (red[2] + red[3]);
}

// ---------------------------------------------------------------------------
// combine halves: logZ = log(f . g) + fbase + gbase; out[b] -= logZ
// ---------------------------------------------------------------------------
__global__ __launch_bounds__(64, 1) void crf_combine(
    const float* __restrict__ ws, float* __restrict__ out)
{
    const int b = blockIdx.x;
    const int j = threadIdx.x;
    const float* fvec = ws;
    const float* gvec = ws + Bn * 64;
    const float* fb   = ws + 2 * Bn * 64;
    const float* gb   = fb + Bn;

    float p = wave_sum(fvec[b * 64 + j] * gvec[b * 64 + j]);
    if (j == 0) out[b] -= (__logf(p) + fb[b] + gb[b]);
}

extern "C" void kernel_launch(void* const* d_in, const int* in_sizes, int n_in,
                              void* d_out, int out_size, void* d_ws, size_t ws_size,
                              hipStream_t stream) {
    const float* inputs = (const float*)d_in[0];
    const float* trans  = (const float*)d_in[1];
    const int*   tags   = (const int*)d_in[2];
    const int*   lens   = (const int*)d_in[3];
    float* out = (float*)d_out;
    float* ws  = (float*)d_ws;

    const size_t need = (size_t)(2 * Bn * 64 + 2 * Bn) * sizeof(float);
    if (ws_size >= need) {
        // fwd/bwd recursion blocks + concurrent score blocks in one dispatch
        crf_main<false><<<3 * Bn, 64, 0, stream>>>(inputs, trans, tags, lens, ws, out);
        crf_combine<<<Bn, 64, 0, stream>>>(ws, out);
    } else {
        // workspace too small: score kernel + single-direction fallback
        crf_scores<<<Bn, 256, 0, stream>>>(inputs, trans, tags, lens, out);
        crf_main<true><<<Bn, 64, 0, stream>>>(inputs, trans, tags, lens, ws, out);
    }
}